// Round 13
// baseline (481.078 us; speedup 1.0000x reference)
//
#include <hip/hip_runtime.h>

// CurvatureLoss: pred (8,4,1024,1024) fp32 -> scalar loss. target unused.
// C=2 cols/lane register-ring sweep, RCHUNK=16. ALL-SCALAR body with
// guaranteed compile-time unrolling: each step is template<int I> do_step,
// called explicitly for I=0..19 -> every ring index is a constant expression
// (rings {P:3, L:5, Rr:2} fully SROA'd to registers; no scratch, no v2f
// scalarization movs). DPP bound_ctrl=1 cross-lane, e0-norm softmax (6 exp),
// per-block slot writes (no atomics), 2 launches.

namespace {
constexpr int H = 1024, W = 1024, B = 8;
constexpr int VALID = 120;            // output cols per wave (64 lanes x 2 - 8)
constexpr int NSTRIPS = 9;            // 9 * 120 = 1080 >= 1024
constexpr int RCHUNK = 16;            // output rows per wave
constexpr int NCHUNKS = H / RCHUNK;   // 64
constexpr int WPB = 2;                // waves per block
constexpr int NTHREADS = 64 * WPB;    // 128
constexpr int NYG = NCHUNKS / WPB;    // 32 y-groups
constexpr int NBLOCKS = NSTRIPS * NYG * B;  // 2304
constexpr int SPG = NSTRIPS * NYG;    // 288 slots per batch
constexpr size_t HW = (size_t)H * W;
}

// DPP cross-lane: neighbor lane's value; OOB lanes read 0 (bound_ctrl=1).
// Lane-0/63 results are never consumed (epilogue gate keeps lanes 2..61).
__device__ __forceinline__ float dpp_left(float x) {   // lane n <- lane n-1
    return __builtin_bit_cast(float,
        __builtin_amdgcn_update_dpp(0, __builtin_bit_cast(int, x),
                                    0x138 /*wave_shr1*/, 0xf, 0xf, true));
}
__device__ __forceinline__ float dpp_right(float x) {  // lane n <- lane n+1
    return __builtin_bit_cast(float,
        __builtin_amdgcn_update_dpp(0, __builtin_bit_cast(int, x),
                                    0x130 /*wave_shl1*/, 0xf, 0xf, true));
}

template <bool RE>
__device__ __forceinline__ void load_row4(const float* __restrict__ basep, int row,
                                          float2 o[4]) {
    const int rc = RE ? min(max(row, 0), H - 1) : row;  // masked later
    const float* p = basep + (size_t)rc * W;
    o[0] = *(const float2*)p;
    o[1] = *(const float2*)(p + HW);
    o[2] = *(const float2*)(p + 2 * HW);
    o[3] = *(const float2*)(p + 3 * HW);
}

// One sweep step, compile-time index I (0..19). Output row y = r0-4+I.
// Ring slots: raw Rr[I%2], prob P[I%3], lap L[I%5] -- all constant indices.
template <int I, bool CE, bool RE>
__device__ __forceinline__ void do_step(
    const float* __restrict__ basep, int r0,
    bool cOK0, bool cOK1,
    float gxpM0, float gxpM1, float gxmM0, float gxmM1,
    float2 (&Rr)[2][4], float (&P)[3][3][2], float (&L)[5][3][2],
    float (&s0)[3], float (&s1)[3],
    unsigned (&c0)[3], unsigned (&c1)[3]) {

    constexpr int ri = I % 2;
    constexpr int pi = I % 3;
    constexpr int li = I % 5;
    const int y = r0 - 4 + I;

    // 1) e0-normalized softmax of raw row y+3 -> P[pi] (both columns).
    {
        const bool pok = !RE || ((unsigned)(y + 3) < (unsigned)H);
        {   // col 0
            const float b0 = Rr[ri][0].x;
            const float e1 = __expf(Rr[ri][1].x - b0);
            const float e2 = __expf(Rr[ri][2].x - b0);
            const float e3 = __expf(Rr[ri][3].x - b0);
            const float t12 = e1 + e2;
            const float inv = __builtin_amdgcn_rcpf(1.f + (t12 + e3));
            if (CE || RE) {
                const bool ok = pok && cOK0;
                P[pi][0][0] = ok ? e1 * inv : 0.f;
                P[pi][1][0] = ok ? t12 * inv : 0.f;
                P[pi][2][0] = ok ? e3 * inv : 0.f;
            } else {
                P[pi][0][0] = e1 * inv;
                P[pi][1][0] = t12 * inv;
                P[pi][2][0] = e3 * inv;
            }
        }
        {   // col 1
            const float b0 = Rr[ri][0].y;
            const float e1 = __expf(Rr[ri][1].y - b0);
            const float e2 = __expf(Rr[ri][2].y - b0);
            const float e3 = __expf(Rr[ri][3].y - b0);
            const float t12 = e1 + e2;
            const float inv = __builtin_amdgcn_rcpf(1.f + (t12 + e3));
            if (CE || RE) {
                const bool ok = pok && cOK1;
                P[pi][0][1] = ok ? e1 * inv : 0.f;
                P[pi][1][1] = ok ? t12 * inv : 0.f;
                P[pi][2][1] = ok ? e3 * inv : 0.f;
            } else {
                P[pi][0][1] = e1 * inv;
                P[pi][1][1] = t12 * inv;
                P[pi][2][1] = e3 * inv;
            }
        }
    }

    // 2) prefetch raw row y+5 -> Rr[ri] (consumed at step I+2). Last consumed
    //    raw row is r0+18, loaded at I=17 -> gate I < 18.
    if constexpr (I < RCHUNK + 2) {
        load_row4<RE>(basep, y + 5, Rr[ri]);
    }

    // 3) lap row y+2 -> L[li] from prob rows y+1, y+2, y+3.
    {
        const bool lok = !RE || ((unsigned)(y + 2) < (unsigned)H);
#pragma unroll
        for (int f = 0; f < 3; ++f) {
            const float topx = P[(I + 1) % 3][f][0], topy = P[(I + 1) % 3][f][1];
            const float midx = P[(I + 2) % 3][f][0], midy = P[(I + 2) % 3][f][1];
            const float botx = P[pi][f][0],          boty = P[pi][f][1];
            const float lft = dpp_left(midy);    // prob(li0-1)
            const float rgt = dpp_right(midx);   // prob(li0+2)
            float lx = (topx + botx) + (lft + midy) - 4.f * midx;
            float ly = (topy + boty) + (midx + rgt) - 4.f * midy;
            if (CE || RE) {
                lx = (lok && cOK0) ? lx : 0.f;
                ly = (lok && cOK1) ? ly : 0.f;
            }
            L[li][f][0] = lx;
            L[li][f][1] = ly;
        }
    }

    // 4) output row y from lap rows y-2..y+2 (steps 0..3 are warmup).
    if constexpr (I >= 4) {
        const float gypM = (!RE || (y + 1 < H)) ? 1.f : 0.f;
        const float gymM = (!RE || (y >= 1)) ? 1.f : 0.f;
#pragma unroll
        for (int f = 0; f < 3; ++f) {
            const float lm2x = L[(I + 1) % 5][f][0], lm2y = L[(I + 1) % 5][f][1];
            const float lm1x = L[(I + 2) % 5][f][0], lm1y = L[(I + 2) % 5][f][1];
            const float lcx  = L[(I + 3) % 5][f][0], lcy  = L[(I + 3) % 5][f][1];
            const float lp1x = L[(I + 4) % 5][f][0], lp1y = L[(I + 4) % 5][f][1];
            const float lp2x = L[li][f][0],          lp2y = L[li][f][1];
            const float A  = dpp_left(lcy);   // lap(li0-1)
            const float Bm = dpp_left(lcx);   // lap(li0-2)
            const float Bp = dpp_right(lcx);  // lap(li0+2)
            const float Cc = dpp_right(lcy);  // lap(li0+3)
            const float gxx = lcy - A;        // gx at col0
            const float gxy = Bp - lcx;       // gx at col1
            float gxpx = gxy,       gxpy = Cc - lcy;   // gxp.x == gx.y identity
            float gxmx = lcx - Bm,  gxmy = gxx;        // gxm.y == gx.x identity
            if (CE) {
                gxpx *= gxpM0; gxpy *= gxpM1;
                gxmx *= gxmM0; gxmy *= gxmM1;
            }
            const float gyx = lp1x - lm1x;
            const float gyy = lp1y - lm1y;
            float gypx = lp2x - lcx, gypy = lp2y - lcy;
            float gymx = lcx - lm2x, gymy = lcy - lm2y;
            if (RE) {
                gypx *= gypM; gypy *= gypM;
                gymx *= gymM; gymy *= gymM;
            }
            {   // col 0
                const float hxx = 2.f * gxx - gxpx - gxmx;
                const float hxy = gxpx - gxmx;
                const float hyy = 2.f * gyx - gypx - gymx;
                const float ox = 1.f + gxx, oy = 1.f + gyx;
                const float numer = hxx * oy * oy - 2.f * hxy * gxx * gyx
                                  + hyy * ox * ox;
                const float xx = 1.f + gxx * gxx + gyx * gyx;
                const float x3 = xx * xx * xx;
                const float rs = __builtin_amdgcn_rsqf(x3);   // xx^-1.5
                s0[f] += fmaxf(-(numer * rs), 0.f);           // 2x curv; 0.5 later
                c0[f] += (numer < 0.f) ? 1u : 0u;             // == (negc != 0)
            }
            {   // col 1
                const float hxx = 2.f * gxy - gxpy - gxmy;
                const float hxy = gxpy - gxmy;
                const float hyy = 2.f * gyy - gypy - gymy;
                const float ox = 1.f + gxy, oy = 1.f + gyy;
                const float numer = hxx * oy * oy - 2.f * hxy * gxy * gyy
                                  + hyy * ox * ox;
                const float xx = 1.f + gxy * gxy + gyy * gyy;
                const float x3 = xx * xx * xx;
                const float rs = __builtin_amdgcn_rsqf(x3);
                s1[f] += fmaxf(-(numer * rs), 0.f);
                c1[f] += (numer < 0.f) ? 1u : 0u;
            }
        }
    }
}

template <bool CE, bool RE>
__device__ __forceinline__ void sweep(const float* __restrict__ pred,
                                      int b, int strip, int chunk, int lane,
                                      float (&s0)[3], float (&s1)[3],
                                      unsigned (&c0)[3], unsigned (&c1)[3]) {
    const int r0 = chunk * RCHUNK;
    const int li0 = 2 * lane;            // local col index 0..127
    const int col0 = strip * VALID - 4 + li0;
    const int col1 = col0 + 1;
    const int colC = CE ? min(max(col0, 0), W - 2) : col0;  // even -> 8B aligned
    const float* basep = pred + (size_t)b * 4 * HW + colC;

    const bool cOK0 = !CE || ((unsigned)col0 < (unsigned)W);
    const bool cOK1 = !CE || ((unsigned)col1 < (unsigned)W);
    const float gxpM0 = (!CE || (col0 + 1 < W)) ? 1.f : 0.f;
    const float gxpM1 = (!CE || (col1 + 1 < W)) ? 1.f : 0.f;
    const float gxmM0 = (!CE || (col0 >= 1)) ? 1.f : 0.f;
    const float gxmM1 = (!CE || (col1 >= 1)) ? 1.f : 0.f;

    float2 Rr[2][4];     // raw ring  [I%2][channel]
    float P[3][3][2];    // prob ring [I%3][field][col]
    float L[5][3][2];    // lap ring  [I%5][field][col]

    // Prologue: prob(r0-3) -> P[1] (top of step 0), prob(r0-2) -> P[2];
    // raw(r0-1) -> Rr[0], raw(r0) -> Rr[1].
    {
        float2 t[4];
        load_row4<RE>(basep, r0 - 3, t);
        const bool ok = !RE || ((unsigned)(r0 - 3) < (unsigned)H);
        {
            const float e1 = __expf(t[1].x - t[0].x);
            const float e2 = __expf(t[2].x - t[0].x);
            const float e3 = __expf(t[3].x - t[0].x);
            const float t12 = e1 + e2;
            const float inv = __builtin_amdgcn_rcpf(1.f + (t12 + e3));
            const bool k = (!(CE || RE)) || (ok && cOK0);
            P[1][0][0] = k ? e1 * inv : 0.f;
            P[1][1][0] = k ? t12 * inv : 0.f;
            P[1][2][0] = k ? e3 * inv : 0.f;
            const float f1 = __expf(t[1].y - t[0].y);
            const float f2 = __expf(t[2].y - t[0].y);
            const float f3 = __expf(t[3].y - t[0].y);
            const float u12 = f1 + f2;
            const float jnv = __builtin_amdgcn_rcpf(1.f + (u12 + f3));
            const bool k2 = (!(CE || RE)) || (ok && cOK1);
            P[1][0][1] = k2 ? f1 * jnv : 0.f;
            P[1][1][1] = k2 ? u12 * jnv : 0.f;
            P[1][2][1] = k2 ? f3 * jnv : 0.f;
        }
        load_row4<RE>(basep, r0 - 2, t);
        const bool ok2 = !RE || ((unsigned)(r0 - 2) < (unsigned)H);
        {
            const float e1 = __expf(t[1].x - t[0].x);
            const float e2 = __expf(t[2].x - t[0].x);
            const float e3 = __expf(t[3].x - t[0].x);
            const float t12 = e1 + e2;
            const float inv = __builtin_amdgcn_rcpf(1.f + (t12 + e3));
            const bool k = (!(CE || RE)) || (ok2 && cOK0);
            P[2][0][0] = k ? e1 * inv : 0.f;
            P[2][1][0] = k ? t12 * inv : 0.f;
            P[2][2][0] = k ? e3 * inv : 0.f;
            const float f1 = __expf(t[1].y - t[0].y);
            const float f2 = __expf(t[2].y - t[0].y);
            const float f3 = __expf(t[3].y - t[0].y);
            const float u12 = f1 + f2;
            const float jnv = __builtin_amdgcn_rcpf(1.f + (u12 + f3));
            const bool k2 = (!(CE || RE)) || (ok2 && cOK1);
            P[2][0][1] = k2 ? f1 * jnv : 0.f;
            P[2][1][1] = k2 ? u12 * jnv : 0.f;
            P[2][2][1] = k2 ? f3 * jnv : 0.f;
        }
    }
    load_row4<RE>(basep, r0 - 1, Rr[0]);
    load_row4<RE>(basep, r0 + 0, Rr[1]);

#define STEP(I) do_step<I, CE, RE>(basep, r0, cOK0, cOK1, gxpM0, gxpM1, \
                                   gxmM0, gxmM1, Rr, P, L, s0, s1, c0, c1)
    STEP(0);  STEP(1);  STEP(2);  STEP(3);  STEP(4);
    STEP(5);  STEP(6);  STEP(7);  STEP(8);  STEP(9);
    STEP(10); STEP(11); STEP(12); STEP(13); STEP(14);
    STEP(15); STEP(16); STEP(17); STEP(18); STEP(19);
#undef STEP
}

__global__ __launch_bounds__(NTHREADS, 4)
void curvature_sweep(const float* __restrict__ pred,
                     float* __restrict__ S_ws,
                     unsigned int* __restrict__ C_ws) {
    __shared__ float redS[3][WPB];
    __shared__ unsigned int redC[3][WPB];

    const int strip = blockIdx.x;
    const int b = blockIdx.z;
    const int tid = threadIdx.x;
    const int wv = tid >> 6, lane = tid & 63;
    const int chunk = blockIdx.y * WPB + wv;

    const bool ce = (strip == 0) || (strip == NSTRIPS - 1);
    const bool re = (chunk == 0) || (chunk == NCHUNKS - 1);

    float s0[3] = {0.f, 0.f, 0.f}, s1[3] = {0.f, 0.f, 0.f};
    unsigned c0[3] = {0u, 0u, 0u}, c1[3] = {0u, 0u, 0u};
    if (!ce && !re)      sweep<false, false>(pred, b, strip, chunk, lane, s0, s1, c0, c1);
    else if (ce && !re)  sweep<true, false>(pred, b, strip, chunk, lane, s0, s1, c0, c1);
    else if (!ce && re)  sweep<false, true>(pred, b, strip, chunk, lane, s0, s1, c0, c1);
    else                 sweep<true, true>(pred, b, strip, chunk, lane, s0, s1, c0, c1);

    // Epilogue gate (hoisted): valid lanes 2..61 (local cols 4..123); col0 is
    // even so col0 < W covers col1 too.
    const int col0 = strip * VALID - 4 + 2 * lane;
    const bool gOK = (lane >= 2) && (lane <= 61) && (col0 < W);

    // Wave reduction -> LDS -> per-block slot write (no atomics).
#pragma unroll
    for (int f = 0; f < 3; ++f) {
        float v = gOK ? 0.5f * (s0[f] + s1[f]) : 0.f;   // 0.5: denom fold
        unsigned int c = gOK ? (c0[f] + c1[f]) : 0u;
        for (int off = 32; off > 0; off >>= 1) {
            v += __shfl_xor(v, off, 64);
            c += __shfl_xor(c, off, 64);
        }
        if (lane == 0) { redS[f][wv] = v; redC[f][wv] = c; }
    }
    __syncthreads();
    if (tid < 3) {
        float v = 0.f;
        unsigned int c = 0;
        for (int w2 = 0; w2 < WPB; ++w2) { v += redS[tid][w2]; c += redC[tid][w2]; }
        const int bid = (b * NYG + blockIdx.y) * NSTRIPS + strip;
        S_ws[bid * 3 + tid] = v;
        C_ws[bid * 3 + tid] = c;
    }
}

// Reduce 2304 block-slots -> 24 (b,field) groups -> loss.
__global__ __launch_bounds__(256)
void finalize_kernel(const float* __restrict__ S_ws,
                     const unsigned int* __restrict__ C_ws,
                     float* __restrict__ out) {
    __shared__ float ls[8][32];
    __shared__ unsigned int lcn[8][32];
    __shared__ float qv[32];
    const int t = threadIdx.x;
    const int g = t & 31;        // group id: b*3+f for g<24
    const int j = t >> 5;        // 0..7
    float s = 0.f;
    unsigned int c = 0;
    if (g < 24) {
        const int b = g / 3, f = g - 3 * b;
        const int base = b * SPG;
        for (int m = 0; m < SPG / 8; ++m) {       // 36 slots per thread
            const int k = base + j * (SPG / 8) + m;
            s += S_ws[k * 3 + f];
            c += C_ws[k * 3 + f];
        }
    }
    ls[j][g] = s;
    lcn[j][g] = c;
    __syncthreads();
    if (t < 32) {
        float ss = 0.f;
        unsigned int cc = 0;
        for (int r = 0; r < 8; ++r) { ss += ls[r][t]; cc += lcn[r][t]; }
        qv[t] = (cc > 0) ? ss / (float)cc : 0.f;  // max(c,1)==c when c>0
    }
    __syncthreads();
    if (t == 0) {
        float tot = 0.f;
        for (int g2 = 0; g2 < 24; ++g2) tot += qv[g2];
        out[0] = tot;
    }
}

extern "C" void kernel_launch(void* const* d_in, const int* in_sizes, int n_in,
                              void* d_out, int out_size, void* d_ws, size_t ws_size,
                              hipStream_t stream) {
    const float* pred = (const float*)d_in[0];
    float* S_ws = (float*)d_ws;
    unsigned int* C_ws = (unsigned int*)((char*)d_ws + NBLOCKS * 3 * sizeof(float));
    float* out = (float*)d_out;

    dim3 grid(NSTRIPS, NYG, B);
    hipLaunchKernelGGL(curvature_sweep, grid, dim3(NTHREADS), 0, stream,
                       pred, S_ws, C_ws);
    hipLaunchKernelGGL(finalize_kernel, dim3(1), dim3(256), 0, stream,
                       S_ws, C_ws, out);
}

// Round 14
// 394.515 us; speedup vs baseline: 1.2194x; 1.2194x over previous
//
#include <hip/hip_runtime.h>

// CurvatureLoss: pred (8,4,1024,1024) fp32 -> scalar loss. target unused.
// C=1 col/lane register-ring sweep for LOW VGPR -> high occupancy (TLP):
// rings P[3][3], L[5][3], Rr[2][4] (scalar, 2-D, full unroll -> SROA).
// 18 strips x 58 valid cols, RCHUNK=16, 9216 waves (9/SIMD demanded).
// +-1 col via DPP bound_ctrl=1; +-2 via chained DPP. e0-norm softmax.
// Per-block slot writes (no atomics), 2 launches.

namespace {
constexpr int H = 1024, W = 1024, B = 8;
constexpr int VALID = 58;             // valid output cols per wave (64 - 6)
constexpr int NSTRIPS = 18;           // 18 * 58 = 1044 >= 1024
constexpr int RCHUNK = 16;            // output rows per wave
constexpr int NCHUNKS = H / RCHUNK;   // 64
constexpr int WPB = 2;                // waves per block
constexpr int NTHREADS = 64 * WPB;    // 128
constexpr int NYG = NCHUNKS / WPB;    // 32 y-groups
constexpr int NBLOCKS = NSTRIPS * NYG * B;  // 4608
constexpr int SPG = NSTRIPS * NYG;    // 576 slots per batch
constexpr size_t HW = (size_t)H * W;
}

// DPP cross-lane: neighbor lane's value; OOB lanes read 0 (bound_ctrl=1).
// Wrong values only ever land in lanes outside the consumed range (see gates).
__device__ __forceinline__ float dpp_left(float x) {   // lane n <- lane n-1
    return __builtin_bit_cast(float,
        __builtin_amdgcn_update_dpp(0, __builtin_bit_cast(int, x),
                                    0x138 /*wave_shr1*/, 0xf, 0xf, true));
}
__device__ __forceinline__ float dpp_right(float x) {  // lane n <- lane n+1
    return __builtin_bit_cast(float,
        __builtin_amdgcn_update_dpp(0, __builtin_bit_cast(int, x),
                                    0x130 /*wave_shl1*/, 0xf, 0xf, true));
}

template <bool RE>
__device__ __forceinline__ void load_row4(const float* __restrict__ basep, int row,
                                          float o[4]) {
    const int rc = RE ? min(max(row, 0), H - 1) : row;  // masked later
    const float* p = basep + (size_t)rc * W;
    o[0] = p[0];
    o[1] = p[HW];
    o[2] = p[2 * HW];
    o[3] = p[3 * HW];
}

template <bool CE, bool RE>
__device__ __forceinline__ void sweep(const float* __restrict__ pred,
                                      int b, int strip, int chunk, int lane,
                                      float (&sac)[3], unsigned (&cac)[3]) {
    const int r0 = chunk * RCHUNK;
    const int col = strip * VALID - 3 + lane;
    const int colC = CE ? min(max(col, 0), W - 1) : col;
    const float* basep = pred + (size_t)b * 4 * HW + colC;

    const bool cOK = !CE || ((unsigned)col < (unsigned)W);
    const float gxpM = (!CE || (col + 1 < W)) ? 1.f : 0.f;
    const float gxmM = (!CE || (col >= 1)) ? 1.f : 0.f;

    float P[3][3];   // prob ring [i%3][field]
    float L[5][3];   // lap ring  [i%5][field]
    float Rr[2][4];  // raw ring  [i%2][channel], prefetch depth 2

    // Prologue: prob(r0-3) -> P[1], prob(r0-2) -> P[2];
    //           raw(r0-1) -> Rr[0], raw(r0) -> Rr[1].
#pragma unroll
    for (int q = 0; q < 2; ++q) {
        float t[4];
        load_row4<RE>(basep, r0 - 3 + q, t);
        const bool ok = !RE || ((unsigned)(r0 - 3 + q) < (unsigned)H);
        const float e1 = __expf(t[1] - t[0]);
        const float e2 = __expf(t[2] - t[0]);
        const float e3 = __expf(t[3] - t[0]);
        const float t12 = e1 + e2;
        const float inv = __builtin_amdgcn_rcpf(1.f + (t12 + e3));
        const bool k = (!(CE || RE)) || (ok && cOK);
        P[1 + q][0] = k ? e1 * inv : 0.f;
        P[1 + q][1] = k ? t12 * inv : 0.f;
        P[1 + q][2] = k ? e3 * inv : 0.f;
    }
    load_row4<RE>(basep, r0 - 1, Rr[0]);
    load_row4<RE>(basep, r0 + 0, Rr[1]);

#pragma unroll
    for (int i = 0; i < RCHUNK + 4; ++i) {        // 20 steps, fully unrolled
        const int y = r0 - 4 + i;                  // output row of this step
        // 1) e0-normalized softmax of raw row y+3 -> P[i%3]
        {
            const bool pok = !RE || ((unsigned)(y + 3) < (unsigned)H);
            const float e1 = __expf(Rr[i % 2][1] - Rr[i % 2][0]);
            const float e2 = __expf(Rr[i % 2][2] - Rr[i % 2][0]);
            const float e3 = __expf(Rr[i % 2][3] - Rr[i % 2][0]);
            const float t12 = e1 + e2;
            const float inv = __builtin_amdgcn_rcpf(1.f + (t12 + e3));
            if (CE || RE) {
                const bool k = pok && cOK;
                P[i % 3][0] = k ? e1 * inv : 0.f;
                P[i % 3][1] = k ? t12 * inv : 0.f;
                P[i % 3][2] = k ? e3 * inv : 0.f;
            } else {
                P[i % 3][0] = e1 * inv;
                P[i % 3][1] = t12 * inv;
                P[i % 3][2] = e3 * inv;
            }
        }
        // 2) prefetch raw row y+5 -> Rr[i%2] (consumed at step i+2);
        //    last consumed raw row is r0+18, loaded at i=17.
        if (i < RCHUNK + 2) load_row4<RE>(basep, y + 5, Rr[i % 2]);
        // 3) lap row y+2 -> L[i%5] from prob rows y+1, y+2, y+3
        {
            const bool lok = !RE || ((unsigned)(y + 2) < (unsigned)H);
#pragma unroll
            for (int f = 0; f < 3; ++f) {
                const float top = P[(i + 1) % 3][f];
                const float mid = P[(i + 2) % 3][f];
                const float bot = P[i % 3][f];
                const float lft = dpp_left(mid);
                const float rgt = dpp_right(mid);
                float l = (top + bot) + (lft + rgt) - 4.f * mid;
                if (CE || RE) l = (lok && cOK) ? l : 0.f;
                L[i % 5][f] = l;
            }
        }
        // 4) output row y from lap rows y-2..y+2 (steps 0..3: warmup)
        if (i >= 4) {
            const float gypM = (!RE || (y + 1 < H)) ? 1.f : 0.f;
            const float gymM = (!RE || (y >= 1)) ? 1.f : 0.f;
#pragma unroll
            for (int f = 0; f < 3; ++f) {
                const float lc  = L[(i + 3) % 5][f];
                const float lm  = dpp_left(lc);    // lap(x-1)
                const float rp  = dpp_right(lc);   // lap(x+1)
                const float lm2 = dpp_left(lm);    // lap(x-2)
                const float rp2 = dpp_right(rp);   // lap(x+2)
                const float gx  = rp - lm;
                const float gy  = L[(i + 4) % 5][f] - L[(i + 2) % 5][f];
                float gxp = rp2 - lc;
                float gxm = lc - lm2;
                if (CE) { gxp *= gxpM; gxm *= gxmM; }
                float gyp = L[i % 5][f] - lc;
                float gym = lc - L[(i + 1) % 5][f];
                if (RE) { gyp *= gypM; gym *= gymM; }
                const float hxx = 2.f * gx - gxp - gxm;
                const float hxy = gxp - gxm;
                const float hyy = 2.f * gy - gyp - gym;
                const float ox = 1.f + gx, oy = 1.f + gy;
                const float numer = hxx * oy * oy - 2.f * hxy * gx * gy
                                  + hyy * ox * ox;
                const float xx = 1.f + gx * gx + gy * gy;
                const float x3 = xx * xx * xx;
                const float rs = __builtin_amdgcn_rsqf(x3);   // xx^-1.5
                sac[f] += fmaxf(-(numer * rs), 0.f);          // 2x curv; 0.5 later
                cac[f] += (numer < 0.f) ? 1u : 0u;            // == (negc != 0)
            }
        }
    }
}

__global__ __launch_bounds__(NTHREADS, 6)
void curvature_sweep(const float* __restrict__ pred,
                     float* __restrict__ S_ws,
                     unsigned int* __restrict__ C_ws) {
    __shared__ float redS[3][WPB];
    __shared__ unsigned int redC[3][WPB];

    const int strip = blockIdx.x;
    const int b = blockIdx.z;
    const int tid = threadIdx.x;
    const int wv = tid >> 6, lane = tid & 63;
    const int chunk = blockIdx.y * WPB + wv;

    const bool ce = (strip == 0) || (strip == NSTRIPS - 1);
    const bool re = (chunk == 0) || (chunk == NCHUNKS - 1);

    float sac[3] = {0.f, 0.f, 0.f};
    unsigned cac[3] = {0u, 0u, 0u};
    if (!ce && !re)      sweep<false, false>(pred, b, strip, chunk, lane, sac, cac);
    else if (ce && !re)  sweep<true, false>(pred, b, strip, chunk, lane, sac, cac);
    else if (!ce && re)  sweep<false, true>(pred, b, strip, chunk, lane, sac, cac);
    else                 sweep<true, true>(pred, b, strip, chunk, lane, sac, cac);

    // Epilogue gate (hoisted): valid lanes 3..60 (halo 3 each side) and
    // in-image column.
    const int col = strip * VALID - 3 + lane;
    const bool gOK = (lane >= 3) && (lane <= 60) && (col < W);

    // Wave reduction -> LDS -> per-block slot write (no atomics).
#pragma unroll
    for (int f = 0; f < 3; ++f) {
        float v = gOK ? 0.5f * sac[f] : 0.f;   // 0.5: denominator fold
        unsigned int c = gOK ? cac[f] : 0u;
        for (int off = 32; off > 0; off >>= 1) {
            v += __shfl_xor(v, off, 64);
            c += __shfl_xor(c, off, 64);
        }
        if (lane == 0) { redS[f][wv] = v; redC[f][wv] = c; }
    }
    __syncthreads();
    if (tid < 3) {
        float v = 0.f;
        unsigned int c = 0;
        for (int w2 = 0; w2 < WPB; ++w2) { v += redS[tid][w2]; c += redC[tid][w2]; }
        const int bid = (b * NYG + blockIdx.y) * NSTRIPS + strip;
        S_ws[bid * 3 + tid] = v;
        C_ws[bid * 3 + tid] = c;
    }
}

// Reduce 4608 block-slots -> 24 (b,field) groups -> loss.
__global__ __launch_bounds__(256)
void finalize_kernel(const float* __restrict__ S_ws,
                     const unsigned int* __restrict__ C_ws,
                     float* __restrict__ out) {
    __shared__ float ls[8][32];
    __shared__ unsigned int lcn[8][32];
    __shared__ float qv[32];
    const int t = threadIdx.x;
    const int g = t & 31;        // group id: b*3+f for g<24
    const int j = t >> 5;        // 0..7
    float s = 0.f;
    unsigned int c = 0;
    if (g < 24) {
        const int b = g / 3, f = g - 3 * b;
        const int base = b * SPG;
        for (int m = 0; m < SPG / 8; ++m) {       // 72 slots per thread
            const int k = base + j * (SPG / 8) + m;
            s += S_ws[k * 3 + f];
            c += C_ws[k * 3 + f];
        }
    }
    ls[j][g] = s;
    lcn[j][g] = c;
    __syncthreads();
    if (t < 32) {
        float ss = 0.f;
        unsigned int cc = 0;
        for (int r = 0; r < 8; ++r) { ss += ls[r][t]; cc += lcn[r][t]; }
        qv[t] = (cc > 0) ? ss / (float)cc : 0.f;  // max(c,1)==c when c>0
    }
    __syncthreads();
    if (t == 0) {
        float tot = 0.f;
        for (int g2 = 0; g2 < 24; ++g2) tot += qv[g2];
        out[0] = tot;
    }
}

extern "C" void kernel_launch(void* const* d_in, const int* in_sizes, int n_in,
                              void* d_out, int out_size, void* d_ws, size_t ws_size,
                              hipStream_t stream) {
    const float* pred = (const float*)d_in[0];
    float* S_ws = (float*)d_ws;
    unsigned int* C_ws = (unsigned int*)((char*)d_ws + NBLOCKS * 3 * sizeof(float));
    float* out = (float*)d_out;

    dim3 grid(NSTRIPS, NYG, B);
    hipLaunchKernelGGL(curvature_sweep, grid, dim3(NTHREADS), 0, stream,
                       pred, S_ws, C_ws);
    hipLaunchKernelGGL(finalize_kernel, dim3(1), dim3(256), 0, stream,
                       S_ws, C_ws, out);
}